// Round 4
// baseline (365.496 us; speedup 1.0000x reference)
//
#include <hip/hip_runtime.h>
#include <math.h>

#define NB 8
#define NP 19248
#define NC 81
#define NOBJ 8
#define NK 32
#define PHD 138
#define PWD 138
#define NPX (PHD * PWD)   // 19044
#define IH 550
#define IW 550
#define NBLK 76           // ceil(NP/256)
#define MROWG 9624        // (NB*NP)/16 row-groups for mark
#define MGRID 1203        // mark grid: 8 row-groups per block

typedef short v8s __attribute__((ext_vector_type(8)));
typedef float v4f __attribute__((ext_vector_type(4)));

__device__ __forceinline__ float wave_sum(float v) {
  #pragma unroll
  for (int o = 32; o >= 1; o >>= 1) v += __shfl_xor(v, o);
  return v;
}
__device__ __forceinline__ int wave_sum_i(int v) {
  #pragma unroll
  for (int o = 32; o >= 1; o >>= 1) v += __shfl_xor(v, o);
  return v;
}
__device__ __forceinline__ unsigned short f2bf(float f) {
  unsigned u = __float_as_uint(f);
  u = (u + 0x7fffu + ((u >> 16) & 1u)) >> 16;
  return (unsigned short)u;
}

// grid (76, NB): one prior per thread. Per-prior max/arg + per-gt argmax via packed u64 atomicMax.
__global__ __launch_bounds__(256) void match1_kernel(
    const float* __restrict__ priors, const float* __restrict__ box_gt,
    float* __restrict__ prior_max, int* __restrict__ prior_arg,
    unsigned long long* __restrict__ forced)
{
  int b = blockIdx.y, tid = threadIdx.x;
  int p = blockIdx.x * 256 + tid;
  int lane = tid & 63;
  __shared__ float gx1[NOBJ], gy1[NOBJ], gx2[NOBJ], gy2[NOBJ], garea[NOBJ];
  if (tid < NOBJ) {
    const float* g = box_gt + (b * NOBJ + tid) * 4;
    float x1 = g[0], y1 = g[1], x2 = g[2], y2 = g[3];
    gx1[tid] = x1; gy1[tid] = y1; gx2[tid] = x2; gy2[tid] = y2;
    garea[tid] = (x2 - x1) * (y2 - y1);
  }
  __syncthreads();

  bool act = p < NP;
  float dx1 = 0, dy1 = 0, dx2 = 0, dy2 = 0, darea = 1.f;
  if (act) {
    const float* pr = priors + p * 4;
    float cx = pr[0], cy = pr[1], w = pr[2], h = pr[3];
    dx1 = cx - w * 0.5f; dy1 = cy - h * 0.5f;
    dx2 = cx + w * 0.5f; dy2 = cy + h * 0.5f;
    darea = (dx2 - dx1) * (dy2 - dy1);
  }
  float pmax = -1.f; int parg = 0;
  unsigned long long pk[NOBJ];
  #pragma unroll
  for (int j = 0; j < NOBJ; j++) {
    float ix = fmaxf(fminf(gx2[j], dx2) - fmaxf(gx1[j], dx1), 0.f);
    float iy = fmaxf(fminf(gy2[j], dy2) - fmaxf(gy1[j], dy1), 0.f);
    float inter = ix * iy;
    float iou = inter / (garea[j] + darea - inter);
    if (j == 0) { pmax = iou; parg = 0; }
    else if (iou > pmax) { pmax = iou; parg = j; }   // strict > : first-index tie-break
    pk[j] = act ? ((((unsigned long long)__float_as_uint(iou)) << 32)
                   | (unsigned long long)(0x7fffffffu - (unsigned)p))
                : 0ull;
  }
  if (act) {
    prior_max[b * NP + p] = pmax;
    prior_arg[b * NP + p] = parg;
  }
  #pragma unroll
  for (int j = 0; j < NOBJ; j++) {
    unsigned long long v = pk[j];
    #pragma unroll
    for (int o = 32; o >= 1; o >>= 1) {
      unsigned long long ov = __shfl_xor(v, o);
      if (ov > v) v = ov;
    }
    if (lane == 0) atomicMax(&forced[b * NOBJ + j], v);
  }
}

// grid (76, NB): forced-match override (later j wins) + conf + smooth-L1 box loss + block pos count.
__global__ __launch_bounds__(256) void conf_kernel(
    const float* __restrict__ priors, const float* __restrict__ box_gt,
    const int* __restrict__ class_gt, const float* __restrict__ box_p,
    const float* __restrict__ prior_max, int* __restrict__ prior_arg,
    const unsigned long long* __restrict__ forced,
    int* __restrict__ conf, int* __restrict__ blkcnt, float* accum)
{
  int b = blockIdx.y, bx = blockIdx.x, tid = threadIdx.x;
  int p = bx * 256 + tid;
  int lane = tid & 63, wid = tid >> 6;
  __shared__ int s_fi[NOBJ];
  __shared__ float lbw[4];
  __shared__ int pcw[4];
  if (tid < NOBJ)
    s_fi[tid] = 0x7fffffff - (int)(forced[b * NOBJ + tid] & 0xffffffffull);
  __syncthreads();
  float lb = 0.f;
  bool flag = false;
  if (p < NP) {
    float m = prior_max[b * NP + p];
    int j = prior_arg[b * NP + p];
    int ov = -1;
    #pragma unroll
    for (int jj = 0; jj < NOBJ; jj++)
      if (p == s_fi[jj]) ov = jj;      // later j wins
    if (ov >= 0) { m = 2.0f; j = ov; prior_arg[b * NP + p] = ov; }
    int cf = class_gt[b * NOBJ + j] + 1;
    if (m < 0.5f) cf = -1;
    if (m < 0.4f) cf = 0;
    conf[b * NP + p] = cf;
    flag = cf > 0;
    if (flag) {
      const float* g = box_gt + (b * NOBJ + j) * 4;
      float x1 = g[0], y1 = g[1], x2 = g[2], y2 = g[3];
      const float* pr = priors + p * 4;
      float pcx = pr[0], pcy = pr[1], prw = pr[2], prh = pr[3];
      float o4[4];
      o4[0] = ((x1 + x2) * 0.5f - pcx) / (0.1f * prw);
      o4[1] = ((y1 + y2) * 0.5f - pcy) / (0.1f * prh);
      o4[2] = logf((x2 - x1) / prw) / 0.2f;
      o4[3] = logf((y2 - y1) / prh) / 0.2f;
      const float* bp = box_p + (b * NP + p) * 4;
      #pragma unroll
      for (int c = 0; c < 4; c++) {
        float d = fabsf(bp[c] - o4[c]);
        lb += (d < 1.f) ? 0.5f * d * d : d - 0.5f;
      }
    }
  }
  unsigned long long bm = __ballot(flag);
  lb = wave_sum(lb);
  if (lane == 0) { lbw[wid] = lb; pcw[wid] = __popcll(bm); }
  __syncthreads();
  if (tid == 0) {
    atomicAdd(&accum[0], lbw[0] + lbw[1] + lbw[2] + lbw[3]);
    blkcnt[b * NBLK + bx] = pcw[0] + pcw[1] + pcw[2] + pcw[3];
  }
}

// grid (76, NB): ordered compaction using blkcnt prefix; last block writes npos/nneg/scale.
__global__ __launch_bounds__(256) void scatter_kernel(
    const int* __restrict__ conf, const int* __restrict__ blkcnt,
    int* __restrict__ pos_list, int* __restrict__ npos_arr,
    int* __restrict__ nneg_arr, float* __restrict__ scale_arr)
{
  int bx = blockIdx.x, b = blockIdx.y, tid = threadIdx.x;
  int lane = tid & 63, wid = tid >> 6;
  __shared__ int s_pre;
  __shared__ int wc[4];
  if (tid < 64) {
    int s = 0;
    if (tid < bx) s += blkcnt[b * NBLK + tid];
    int t2 = tid + 64;
    if (t2 < bx) s += blkcnt[b * NBLK + t2];
    s = wave_sum_i(s);
    if (tid == 0) s_pre = s;
  }
  int p = bx * 256 + tid;
  bool flag = (p < NP) && (conf[b * NP + p] > 0);
  unsigned long long m = __ballot(flag);
  if (lane == 0) wc[wid] = __popcll(m);
  __syncthreads();
  int base = s_pre;
  for (int w = 0; w < wid; w++) base += wc[w];
  int idx = base + __popcll(m & ((1ull << lane) - 1ull));
  if (flag && idx < 128) pos_list[b * 128 + idx] = p;
  if (bx == NBLK - 1 && tid == 0) {
    int np = s_pre + wc[0] + wc[1] + wc[2] + wc[3];
    npos_arr[b] = np;
    int nn = 3 * np; if (nn > NP - 1) nn = NP - 1;
    nneg_arr[b] = nn;
    scale_arr[b] = (np > 100) ? (float)np / 100.0f : 1.0f;
  }
}

// mark v2: grid-stride over 9624 row-groups with 1203 blocks (dispatch-rate fix).
// Per-row arithmetic and lane mapping identical to v1 -> bit-identical marks.
// Positive-NLL accumulated per block, one atomic at the end.
__global__ __launch_bounds__(256) void mark_kernel(
    const float* __restrict__ class_p, const int* __restrict__ conf,
    float* __restrict__ marks, float* accum)
{
  int lane = threadIdx.x & 63, wv = threadIdx.x >> 6;
  int sub = lane & 15, grp = lane >> 4;
  __shared__ float sred[4];
  float acc1 = 0.f;
  for (int gblk = blockIdx.x; gblk < MROWG; gblk += MGRID) {
    int row = gblk * 16 + wv * 4 + grp;
    const float* cp = class_p + (size_t)row * NC;
    float v[6];
    #pragma unroll
    for (int k = 0; k < 6; k++) {
      int c = sub + 16 * k;
      v[k] = (c < NC) ? cp[c] : -INFINITY;
    }
    float m = v[0];
    #pragma unroll
    for (int k = 1; k < 6; k++) m = fmaxf(m, v[k]);
    #pragma unroll
    for (int o = 1; o < 16; o <<= 1) m = fmaxf(m, __shfl_xor(m, o));
    float s = 0.f;
    #pragma unroll
    for (int k = 0; k < 6; k++) s += __expf(v[k] - m);
    #pragma unroll
    for (int o = 1; o < 16; o <<= 1) s += __shfl_xor(s, o);
    float lse = m + __logf(s);
    if (sub == 0) {
      int cf = conf[row];
      marks[row] = (cf != 0) ? 0.f : (lse - v[0]);
      if (cf > 0) acc1 += lse - cp[cf];
    }
  }
  acc1 = wave_sum(acc1);
  if (lane == 0) sred[wv] = acc1;
  __syncthreads();
  if (threadIdx.x == 0)
    atomicAdd(&accum[1], sred[0] + sred[1] + sred[2] + sred[3]);
}

// Per batch, 256 threads x 76 regs: 31-step binary search on uint bits; sum of top-k marks.
__global__ __launch_bounds__(256) void select_kernel(
    const float* __restrict__ marks, const int* __restrict__ nneg_arr, float* accum)
{
  int b = blockIdx.x, tid = threadIdx.x;
  int lane = tid & 63, wid = tid >> 6;
  float v[NBLK];
  #pragma unroll
  for (int i = 0; i < NBLK; i++) {
    int p = i * 256 + tid;
    v[i] = (p < NP) ? marks[b * NP + p] : 0.f;  // pad 0: midpoints > 0, pads never counted
  }
  int k = nneg_arr[b];
  __shared__ unsigned slo, shi;
  __shared__ int wred[4];
  __shared__ float fred[4];
  if (tid == 0) { slo = 0u; shi = 0x7f800000u; }
  __syncthreads();
  while (true) {
    unsigned lo = slo, hi = shi;
    if (hi - lo <= 1u) break;
    unsigned mid = lo + ((hi - lo) >> 1);
    float fmid = __uint_as_float(mid);
    int cnt = 0;
    #pragma unroll
    for (int i = 0; i < NBLK; i++) cnt += (v[i] >= fmid) ? 1 : 0;
    cnt = wave_sum_i(cnt);
    if (lane == 0) wred[wid] = cnt;
    __syncthreads();
    if (tid == 0) {
      int tot = wred[0] + wred[1] + wred[2] + wred[3];
      if (tot >= k) slo = mid; else shi = mid;
    }
    __syncthreads();
  }
  float thr = __uint_as_float(slo);
  float s = 0.f;
  #pragma unroll
  for (int i = 0; i < NBLK; i++) if (v[i] >= thr) s += v[i];
  s = wave_sum(s);
  if (lane == 0) fred[wid] = s;
  __syncthreads();
  if (tid == 0) atomicAdd(&accum[1], fred[0] + fred[1] + fred[2] + fred[3]);
}

// Separable antialiased resize v4. Block = (plane-group of 4, oy-group of 6).
// Each wave owns one plane; also counts the 1-bits it writes -> gtot[plane]
// (used by maskloss to fold out-of-box BCE into closed-form constants).
// Arithmetic identical to v3 -> bit-exact binary output.
__global__ __launch_bounds__(256) void resize_kernel(
    const float* __restrict__ mask_gt, unsigned char* __restrict__ dmp,
    int* __restrict__ gtot)
{
  int pg = blockIdx.x;         // plane group 0..15
  int tid = threadIdx.x;
  int wv = tid >> 6, lane = tid & 63;
  int bn = pg * 4 + wv;        // plane 0..63

  __shared__ float tmp[4][IW];       // per-wave vertical-pass rows (8800 B)
  __shared__ float s_wx[PWD][9];     // horizontal weights, padded stride 9 (4968 B)
  __shared__ float s_wsx[PWD];
  __shared__ int   s_xlo[PWD];

  const float ks = (float)IH / (float)PHD;  // 550/138

  // horizontal weights: once per block (threads 0..137)
  if (tid < PWD) {
    int ox = tid;
    float sx = (ox + 0.5f) * ks - 0.5f;
    int xlo = (int)ceilf(sx - ks); if (xlo < 0) xlo = 0;
    int xhi = (int)floorf(sx + ks); if (xhi > IW - 1) xhi = IW - 1;
    int nx = xhi - xlo;
    float wsx = 0.f;
    #pragma unroll
    for (int i = 0; i < 8; i++) {
      float w = (i <= nx) ? fmaxf(0.f, 1.f - fabsf(sx - (float)(xlo + i)) / ks) : 0.f;
      s_wx[ox][i] = w; wsx += w;
    }
    s_xlo[ox] = xlo;
    s_wsx[ox] = wsx;
  }
  __syncthreads();

  const float* mg = mask_gt + (size_t)bn * (IH * IW);
  int ones = 0;

  for (int q = 0; q < 6; ++q) {
    int oy = blockIdx.y * 6 + q;   // 0..137 (138 = 23*6)

    // vertical weights: uniform across the block (same oy)
    float sy = (oy + 0.5f) * ks - 0.5f;
    int ylo = (int)ceilf(sy - ks); if (ylo < 0) ylo = 0;
    int yhi = (int)floorf(sy + ks); if (yhi > IH - 1) yhi = IH - 1;
    int ny = yhi - ylo;   // <= 7
    float wy[8]; float wsy = 0.f;
    #pragma unroll
    for (int j = 0; j < 8; j++) {
      float w = (j <= ny) ? fmaxf(0.f, 1.f - fabsf(sy - (float)(ylo + j)) / ks) : 0.f;
      wy[j] = w; wsy += w;
    }

    // vertical pass: wave wv reduces its plane's 8 rows into tmp[wv][.] (float2 loads).
    const float* rowp[8];
    #pragma unroll
    for (int j = 0; j < 8; j++) {
      int y = ylo + j; if (y > IH - 1) y = IH - 1;
      rowp[j] = mg + (size_t)y * IW;
    }
    for (int x2 = lane; x2 < IW / 2; x2 += 64) {
      float ax = 0.f, ay = 0.f;
      #pragma unroll
      for (int j = 0; j < 8; j++) {
        float2 v = *(const float2*)(rowp[j] + 2 * x2);
        ax += wy[j] * v.x;
        ay += wy[j] * v.y;
      }
      tmp[wv][2 * x2]     = ax;
      tmp[wv][2 * x2 + 1] = ay;
    }
    __syncthreads();   // LDS write->read visibility (tmp strips are wave-private)

    // horizontal pass + threshold: 138 outputs per wave (its own plane)
    unsigned char* op = dmp + (size_t)bn * NPX + (size_t)oy * PWD;
    for (int ox = lane; ox < PWD; ox += 64) {
      int xlo = s_xlo[ox];
      float vsum = 0.f;
      #pragma unroll
      for (int i = 0; i < 8; i++) {
        int xi = xlo + i; if (xi > IW - 1) xi = IW - 1;
        vsum += s_wx[ox][i] * tmp[wv][xi];
      }
      int bit = (vsum > 0.5f * wsy * s_wsx[ox]) ? 1 : 0;
      op[ox] = (unsigned char)bit;
      ones += bit;
    }
    __syncthreads();   // all reads of tmp done before next q overwrites
  }
  ones = wave_sum_i(ones);
  if (lane == 0) atomicAdd(&gtot[bn], ones);
}

// Mask loss v3: one block per (k, b). Only the in-box rectangle is evaluated
// (f32 dot of proto row with coef, softplus BCE); all out-of-box pixels collapse
// to closed-form constants via gt bit counts: loss_k = sum_rect bce
//   + C_POS*(Gtot - Grect) + C_NEGLO*(NPX - rectpx - (Gtot - Grect)).
// ~10x fewer pixel-pairs than the dense MFMA version; f32 dot is strictly more
// accurate than the previous bf16 MFMA logits.
__global__ __launch_bounds__(256) void maskloss_kernel(
    const float* __restrict__ proto_p, const float* __restrict__ coef_p,
    const float* __restrict__ box_gt, const int* __restrict__ pmi,
    const unsigned char* __restrict__ dmp, const int* __restrict__ pos_list,
    const int* __restrict__ npos_arr, const int* __restrict__ gtot,
    const float* __restrict__ scale_arr, float* accum)
{
  int k = blockIdx.x, b = blockIdx.y;
  int tid = threadIdx.x, wv = tid >> 6, lane = tid & 63;
  int np = npos_arr[b];
  int mb = np < 100 ? np : 100;
  if (k >= mb) return;

  int p = pos_list[b * 128 + k];
  int gi = pmi[b * NP + p];
  const float* g = box_gt + (b * NOBJ + gi) * 4;
  float bx1 = g[0], by1 = g[1], bx2 = g[2], by2 = g[3];
  float ax = bx1 * 138.f, bx = bx2 * 138.f;
  float x1 = fminf(ax, bx), x2 = fmaxf(ax, bx);
  x1 = fmaxf(x1 - 1.f, 0.f); x2 = fminf(x2 + 1.f, 138.f);
  float ay = by1 * 138.f, by_ = by2 * 138.f;
  float y1 = fminf(ay, by_), y2 = fmaxf(ay, by_);
  y1 = fmaxf(y1 - 1.f, 0.f); y2 = fminf(y2 + 1.f, 138.f);
  float inv = 1.f / ((bx2 - bx1) * (by2 - by1));

  // integer rect [xs,xe) x [ys,ye): x >= x1 <=> x >= ceil(x1); x < x2 <=> x < ceil(x2)
  int xs = (int)ceilf(x1), xe = (int)ceilf(x2);
  int ys = (int)ceilf(y1), ye = (int)ceilf(y2);
  if (xe < xs) xe = xs;
  if (ye < ys) ye = ys;
  int rectpx = (xe - xs) * (ye - ys);

  // coef to registers (all lanes same values: broadcast loads)
  const float4* c4p = (const float4*)(coef_p + ((size_t)(b * NP) + p) * NK);
  float4 c4[8];
  #pragma unroll
  for (int i = 0; i < 8; i++) c4[i] = c4p[i];

  const float C_POS   = 16.11809565f;     // -log(1e-7)
  const float C_NEGHI = 15.94238515f;     // -log1p(-0.99999988f)
  const float C_NEGLO = 1.00000005e-07f;  // -log1p(-1e-7f)

  const float* protoB = proto_p + (size_t)b * NPX * NK;
  const unsigned char* dpl = dmp + (size_t)(b * NOBJ + gi) * NPX;

  float lsum = 0.f;
  int gcnt = 0;
  for (int y = ys + wv; y < ye; y += 4) {
    int rowb = y * PWD;
    for (int x = xs + lane; x < xe; x += 64) {
      int px = rowb + x;
      const float4* pr = (const float4*)(protoB + (size_t)px * NK);
      float dot = 0.f;
      #pragma unroll
      for (int i = 0; i < 8; i++) {
        float4 v = pr[i];
        dot += v.x * c4[i].x + v.y * c4[i].y + v.z * c4[i].z + v.w * c4[i].w;
      }
      float l = dot;
      float el = __expf(-fabsf(l));
      float sp = fmaxf(l, 0.f) + __logf(1.f + el);
      float t1 = fminf(sp - l, C_POS);
      float t2 = fminf(fmaxf(sp, C_NEGLO), C_NEGHI);
      int gbit = dpl[px];
      gcnt += gbit;
      lsum += gbit ? t1 : t2;
    }
  }

  lsum = wave_sum(lsum);
  gcnt = wave_sum_i(gcnt);
  __shared__ float sl[4];
  __shared__ int sg[4];
  if (lane == 0) { sl[wv] = lsum; sg[wv] = gcnt; }
  __syncthreads();
  if (tid == 0) {
    float L = sl[0] + sl[1] + sl[2] + sl[3];
    int G = sg[0] + sg[1] + sg[2] + sg[3];
    int Gt = gtot[b * NOBJ + gi];
    float outG = (float)(Gt - G);
    float outN = (float)(NPX - rectpx - (Gt - G));
    L += C_POS * outG + C_NEGLO * outN;
    atomicAdd(&accum[2], L * inv * scale_arr[b]);
  }
}

__global__ void finalize_kernel(const float* accum, float* out) {
  out[0] = 1.5f * accum[0] + accum[1] + accum[2] * (6.125f / (138.f * 138.f));
}

extern "C" void kernel_launch(void* const* d_in, const int* in_sizes, int n_in,
                              void* d_out, int out_size, void* d_ws, size_t ws_size,
                              hipStream_t stream) {
  const float* class_p  = (const float*)d_in[0];
  const float* box_p    = (const float*)d_in[1];
  const float* coef_p   = (const float*)d_in[2];
  const float* proto_p  = (const float*)d_in[3];
  const float* priors   = (const float*)d_in[4];
  const float* box_gt   = (const float*)d_in[5];
  const float* mask_gt  = (const float*)d_in[6];
  const int*   class_gt = (const int*)d_in[7];

  char* ws = (char*)d_ws;
  float* prior_max = (float*)(ws + 0);                 // NB*NP f32 = 615936 B
  int*   prior_arg = (int*)(ws + 615936);              // NB*NP i32
  int*   conf      = (int*)(ws + 1231872);             // NB*NP i32
  float* marks     = (float*)(ws + 1847808);           // NB*NP f32
  unsigned char* dmp = (unsigned char*)(ws + 2463744); // NB*NOBJ*NPX u8 = 1218816
  int*   pos_list  = (int*)(ws + 3682560);             // NB*128 i32 = 4096
  int*   npos_arr  = (int*)(ws + 3686656);             // NB i32
  int*   nneg_arr  = (int*)(ws + 3686688);             // NB i32
  float* scale_arr = (float*)(ws + 3686720);           // NB f32
  float* accum     = (float*)(ws + 3686752);           // 4 f32  (memset region start)
  unsigned long long* forced = (unsigned long long*)(ws + 3686768); // NB*NOBJ u64 = 512
  int*   gtot      = (int*)(ws + 3687280);             // NB*NOBJ i32 = 256 (memset'd)
  int*   blkcnt    = (int*)(ws + 3687536);             // NB*NBLK i32 = 2432
  (void)in_sizes; (void)n_in; (void)out_size; (void)ws_size;

  // zero accum (16B) + forced (512B) + gtot (256B) in one memset node
  hipMemsetAsync((void*)accum, 0, 16 + 512 + 256, stream);

  {
    dim3 g(NBLK, NB);
    match1_kernel<<<g, 256, 0, stream>>>(priors, box_gt, prior_max, prior_arg, forced);
    conf_kernel<<<g, 256, 0, stream>>>(priors, box_gt, class_gt, box_p,
                                       prior_max, prior_arg, forced, conf, blkcnt, accum);
    scatter_kernel<<<g, 256, 0, stream>>>(conf, blkcnt, pos_list,
                                          npos_arr, nneg_arr, scale_arr);
  }
  mark_kernel<<<MGRID, 256, 0, stream>>>(class_p, conf, marks, accum);
  select_kernel<<<NB, 256, 0, stream>>>(marks, nneg_arr, accum);
  {
    dim3 g(NB * NOBJ / 4, PHD / 6);   // (plane-group, oy-group)
    resize_kernel<<<g, 256, 0, stream>>>(mask_gt, dmp, gtot);
  }
  {
    dim3 g(112, NB);   // (k slot, batch)
    maskloss_kernel<<<g, 256, 0, stream>>>(proto_p, coef_p, box_gt, prior_arg, dmp,
                                           pos_list, npos_arr, gtot, scale_arr, accum);
  }
  finalize_kernel<<<1, 1, 0, stream>>>(accum, (float*)d_out);
}

// Round 5
// 341.799 us; speedup vs baseline: 1.0693x; 1.0693x over previous
//
#include <hip/hip_runtime.h>
#include <math.h>

#define NB 8
#define NP 19248
#define NC 81
#define NOBJ 8
#define NK 32
#define PHD 138
#define PWD 138
#define NPX (PHD * PWD)   // 19044
#define IH 550
#define IW 550
#define NBLK 76           // ceil(NP/256)
#define MROWG 9624        // (NB*NP)/16 row-groups for mark
#define MGRID 1203        // mark grid: 8 row-groups per block

typedef short v8s __attribute__((ext_vector_type(8)));
typedef float v4f __attribute__((ext_vector_type(4)));

__device__ __forceinline__ float wave_sum(float v) {
  #pragma unroll
  for (int o = 32; o >= 1; o >>= 1) v += __shfl_xor(v, o);
  return v;
}
__device__ __forceinline__ int wave_sum_i(int v) {
  #pragma unroll
  for (int o = 32; o >= 1; o >>= 1) v += __shfl_xor(v, o);
  return v;
}
__device__ __forceinline__ unsigned short f2bf(float f) {
  unsigned u = __float_as_uint(f);
  u = (u + 0x7fffu + ((u >> 16) & 1u)) >> 16;
  return (unsigned short)u;
}

// grid (76, NB): one prior per thread. Per-prior max/arg + per-gt argmax via packed u64 atomicMax.
__global__ __launch_bounds__(256) void match1_kernel(
    const float* __restrict__ priors, const float* __restrict__ box_gt,
    float* __restrict__ prior_max, int* __restrict__ prior_arg,
    unsigned long long* __restrict__ forced)
{
  int b = blockIdx.y, tid = threadIdx.x;
  int p = blockIdx.x * 256 + tid;
  int lane = tid & 63;
  __shared__ float gx1[NOBJ], gy1[NOBJ], gx2[NOBJ], gy2[NOBJ], garea[NOBJ];
  if (tid < NOBJ) {
    const float* g = box_gt + (b * NOBJ + tid) * 4;
    float x1 = g[0], y1 = g[1], x2 = g[2], y2 = g[3];
    gx1[tid] = x1; gy1[tid] = y1; gx2[tid] = x2; gy2[tid] = y2;
    garea[tid] = (x2 - x1) * (y2 - y1);
  }
  __syncthreads();

  bool act = p < NP;
  float dx1 = 0, dy1 = 0, dx2 = 0, dy2 = 0, darea = 1.f;
  if (act) {
    const float* pr = priors + p * 4;
    float cx = pr[0], cy = pr[1], w = pr[2], h = pr[3];
    dx1 = cx - w * 0.5f; dy1 = cy - h * 0.5f;
    dx2 = cx + w * 0.5f; dy2 = cy + h * 0.5f;
    darea = (dx2 - dx1) * (dy2 - dy1);
  }
  float pmax = -1.f; int parg = 0;
  unsigned long long pk[NOBJ];
  #pragma unroll
  for (int j = 0; j < NOBJ; j++) {
    float ix = fmaxf(fminf(gx2[j], dx2) - fmaxf(gx1[j], dx1), 0.f);
    float iy = fmaxf(fminf(gy2[j], dy2) - fmaxf(gy1[j], dy1), 0.f);
    float inter = ix * iy;
    float iou = inter / (garea[j] + darea - inter);
    if (j == 0) { pmax = iou; parg = 0; }
    else if (iou > pmax) { pmax = iou; parg = j; }   // strict > : first-index tie-break
    pk[j] = act ? ((((unsigned long long)__float_as_uint(iou)) << 32)
                   | (unsigned long long)(0x7fffffffu - (unsigned)p))
                : 0ull;
  }
  if (act) {
    prior_max[b * NP + p] = pmax;
    prior_arg[b * NP + p] = parg;
  }
  #pragma unroll
  for (int j = 0; j < NOBJ; j++) {
    unsigned long long v = pk[j];
    #pragma unroll
    for (int o = 32; o >= 1; o >>= 1) {
      unsigned long long ov = __shfl_xor(v, o);
      if (ov > v) v = ov;
    }
    if (lane == 0) atomicMax(&forced[b * NOBJ + j], v);
  }
}

// grid (76, NB): forced-match override (later j wins) + conf + smooth-L1 box loss + block pos count.
__global__ __launch_bounds__(256) void conf_kernel(
    const float* __restrict__ priors, const float* __restrict__ box_gt,
    const int* __restrict__ class_gt, const float* __restrict__ box_p,
    const float* __restrict__ prior_max, int* __restrict__ prior_arg,
    const unsigned long long* __restrict__ forced,
    int* __restrict__ conf, int* __restrict__ blkcnt, float* accum)
{
  int b = blockIdx.y, bx = blockIdx.x, tid = threadIdx.x;
  int p = bx * 256 + tid;
  int lane = tid & 63, wid = tid >> 6;
  __shared__ int s_fi[NOBJ];
  __shared__ float lbw[4];
  __shared__ int pcw[4];
  if (tid < NOBJ)
    s_fi[tid] = 0x7fffffff - (int)(forced[b * NOBJ + tid] & 0xffffffffull);
  __syncthreads();
  float lb = 0.f;
  bool flag = false;
  if (p < NP) {
    float m = prior_max[b * NP + p];
    int j = prior_arg[b * NP + p];
    int ov = -1;
    #pragma unroll
    for (int jj = 0; jj < NOBJ; jj++)
      if (p == s_fi[jj]) ov = jj;      // later j wins
    if (ov >= 0) { m = 2.0f; j = ov; prior_arg[b * NP + p] = ov; }
    int cf = class_gt[b * NOBJ + j] + 1;
    if (m < 0.5f) cf = -1;
    if (m < 0.4f) cf = 0;
    conf[b * NP + p] = cf;
    flag = cf > 0;
    if (flag) {
      const float* g = box_gt + (b * NOBJ + j) * 4;
      float x1 = g[0], y1 = g[1], x2 = g[2], y2 = g[3];
      const float* pr = priors + p * 4;
      float pcx = pr[0], pcy = pr[1], prw = pr[2], prh = pr[3];
      float o4[4];
      o4[0] = ((x1 + x2) * 0.5f - pcx) / (0.1f * prw);
      o4[1] = ((y1 + y2) * 0.5f - pcy) / (0.1f * prh);
      o4[2] = logf((x2 - x1) / prw) / 0.2f;
      o4[3] = logf((y2 - y1) / prh) / 0.2f;
      const float* bp = box_p + (b * NP + p) * 4;
      #pragma unroll
      for (int c = 0; c < 4; c++) {
        float d = fabsf(bp[c] - o4[c]);
        lb += (d < 1.f) ? 0.5f * d * d : d - 0.5f;
      }
    }
  }
  unsigned long long bm = __ballot(flag);
  lb = wave_sum(lb);
  if (lane == 0) { lbw[wid] = lb; pcw[wid] = __popcll(bm); }
  __syncthreads();
  if (tid == 0) {
    atomicAdd(&accum[0], lbw[0] + lbw[1] + lbw[2] + lbw[3]);
    blkcnt[b * NBLK + bx] = pcw[0] + pcw[1] + pcw[2] + pcw[3];
  }
}

// grid (76, NB): ordered compaction using blkcnt prefix; last block writes npos/nneg/scale.
__global__ __launch_bounds__(256) void scatter_kernel(
    const int* __restrict__ conf, const int* __restrict__ blkcnt,
    int* __restrict__ pos_list, int* __restrict__ npos_arr,
    int* __restrict__ nneg_arr, float* __restrict__ scale_arr)
{
  int bx = blockIdx.x, b = blockIdx.y, tid = threadIdx.x;
  int lane = tid & 63, wid = tid >> 6;
  __shared__ int s_pre;
  __shared__ int wc[4];
  if (tid < 64) {
    int s = 0;
    if (tid < bx) s += blkcnt[b * NBLK + tid];
    int t2 = tid + 64;
    if (t2 < bx) s += blkcnt[b * NBLK + t2];
    s = wave_sum_i(s);
    if (tid == 0) s_pre = s;
  }
  int p = bx * 256 + tid;
  bool flag = (p < NP) && (conf[b * NP + p] > 0);
  unsigned long long m = __ballot(flag);
  if (lane == 0) wc[wid] = __popcll(m);
  __syncthreads();
  int base = s_pre;
  for (int w = 0; w < wid; w++) base += wc[w];
  int idx = base + __popcll(m & ((1ull << lane) - 1ull));
  if (flag && idx < 128) pos_list[b * 128 + idx] = p;
  if (bx == NBLK - 1 && tid == 0) {
    int np = s_pre + wc[0] + wc[1] + wc[2] + wc[3];
    npos_arr[b] = np;
    int nn = 3 * np; if (nn > NP - 1) nn = NP - 1;
    nneg_arr[b] = nn;
    scale_arr[b] = (np > 100) ? (float)np / 100.0f : 1.0f;
  }
}

// mark v2: grid-stride over 9624 row-groups with 1203 blocks (dispatch-rate fix).
// Per-row arithmetic and lane mapping identical to v1 -> bit-identical marks.
// Positive-NLL accumulated per block, one atomic at the end.
__global__ __launch_bounds__(256) void mark_kernel(
    const float* __restrict__ class_p, const int* __restrict__ conf,
    float* __restrict__ marks, float* accum)
{
  int lane = threadIdx.x & 63, wv = threadIdx.x >> 6;
  int sub = lane & 15, grp = lane >> 4;
  __shared__ float sred[4];
  float acc1 = 0.f;
  for (int gblk = blockIdx.x; gblk < MROWG; gblk += MGRID) {
    int row = gblk * 16 + wv * 4 + grp;
    const float* cp = class_p + (size_t)row * NC;
    float v[6];
    #pragma unroll
    for (int k = 0; k < 6; k++) {
      int c = sub + 16 * k;
      v[k] = (c < NC) ? cp[c] : -INFINITY;
    }
    float m = v[0];
    #pragma unroll
    for (int k = 1; k < 6; k++) m = fmaxf(m, v[k]);
    #pragma unroll
    for (int o = 1; o < 16; o <<= 1) m = fmaxf(m, __shfl_xor(m, o));
    float s = 0.f;
    #pragma unroll
    for (int k = 0; k < 6; k++) s += __expf(v[k] - m);
    #pragma unroll
    for (int o = 1; o < 16; o <<= 1) s += __shfl_xor(s, o);
    float lse = m + __logf(s);
    if (sub == 0) {
      int cf = conf[row];
      marks[row] = (cf != 0) ? 0.f : (lse - v[0]);
      if (cf > 0) acc1 += lse - cp[cf];
    }
  }
  acc1 = wave_sum(acc1);
  if (lane == 0) sred[wv] = acc1;
  __syncthreads();
  if (threadIdx.x == 0)
    atomicAdd(&accum[1], sred[0] + sred[1] + sred[2] + sred[3]);
}

// Per batch, 256 threads x 76 regs: 31-step binary search on uint bits; sum of top-k marks.
__global__ __launch_bounds__(256) void select_kernel(
    const float* __restrict__ marks, const int* __restrict__ nneg_arr, float* accum)
{
  int b = blockIdx.x, tid = threadIdx.x;
  int lane = tid & 63, wid = tid >> 6;
  float v[NBLK];
  #pragma unroll
  for (int i = 0; i < NBLK; i++) {
    int p = i * 256 + tid;
    v[i] = (p < NP) ? marks[b * NP + p] : 0.f;  // pad 0: midpoints > 0, pads never counted
  }
  int k = nneg_arr[b];
  __shared__ unsigned slo, shi;
  __shared__ int wred[4];
  __shared__ float fred[4];
  if (tid == 0) { slo = 0u; shi = 0x7f800000u; }
  __syncthreads();
  while (true) {
    unsigned lo = slo, hi = shi;
    if (hi - lo <= 1u) break;
    unsigned mid = lo + ((hi - lo) >> 1);
    float fmid = __uint_as_float(mid);
    int cnt = 0;
    #pragma unroll
    for (int i = 0; i < NBLK; i++) cnt += (v[i] >= fmid) ? 1 : 0;
    cnt = wave_sum_i(cnt);
    if (lane == 0) wred[wid] = cnt;
    __syncthreads();
    if (tid == 0) {
      int tot = wred[0] + wred[1] + wred[2] + wred[3];
      if (tot >= k) slo = mid; else shi = mid;
    }
    __syncthreads();
  }
  float thr = __uint_as_float(slo);
  float s = 0.f;
  #pragma unroll
  for (int i = 0; i < NBLK; i++) if (v[i] >= thr) s += v[i];
  s = wave_sum(s);
  if (lane == 0) fred[wid] = s;
  __syncthreads();
  if (tid == 0) atomicAdd(&accum[1], fred[0] + fred[1] + fred[2] + fred[3]);
}

// Separable antialiased resize v4. Block = (plane-group of 4, oy-group of 6).
// Each wave owns one plane; also counts the 1-bits it writes -> gtot[plane].
// Arithmetic identical to v3 -> bit-exact binary output.
__global__ __launch_bounds__(256) void resize_kernel(
    const float* __restrict__ mask_gt, unsigned char* __restrict__ dmp,
    int* __restrict__ gtot)
{
  int pg = blockIdx.x;         // plane group 0..15
  int tid = threadIdx.x;
  int wv = tid >> 6, lane = tid & 63;
  int bn = pg * 4 + wv;        // plane 0..63

  __shared__ float tmp[4][IW];       // per-wave vertical-pass rows (8800 B)
  __shared__ float s_wx[PWD][9];     // horizontal weights, padded stride 9 (4968 B)
  __shared__ float s_wsx[PWD];
  __shared__ int   s_xlo[PWD];

  const float ks = (float)IH / (float)PHD;  // 550/138

  // horizontal weights: once per block (threads 0..137)
  if (tid < PWD) {
    int ox = tid;
    float sx = (ox + 0.5f) * ks - 0.5f;
    int xlo = (int)ceilf(sx - ks); if (xlo < 0) xlo = 0;
    int xhi = (int)floorf(sx + ks); if (xhi > IW - 1) xhi = IW - 1;
    int nx = xhi - xlo;
    float wsx = 0.f;
    #pragma unroll
    for (int i = 0; i < 8; i++) {
      float w = (i <= nx) ? fmaxf(0.f, 1.f - fabsf(sx - (float)(xlo + i)) / ks) : 0.f;
      s_wx[ox][i] = w; wsx += w;
    }
    s_xlo[ox] = xlo;
    s_wsx[ox] = wsx;
  }
  __syncthreads();

  const float* mg = mask_gt + (size_t)bn * (IH * IW);
  int ones = 0;

  for (int q = 0; q < 6; ++q) {
    int oy = blockIdx.y * 6 + q;   // 0..137 (138 = 23*6)

    // vertical weights: uniform across the block (same oy)
    float sy = (oy + 0.5f) * ks - 0.5f;
    int ylo = (int)ceilf(sy - ks); if (ylo < 0) ylo = 0;
    int yhi = (int)floorf(sy + ks); if (yhi > IH - 1) yhi = IH - 1;
    int ny = yhi - ylo;   // <= 7
    float wy[8]; float wsy = 0.f;
    #pragma unroll
    for (int j = 0; j < 8; j++) {
      float w = (j <= ny) ? fmaxf(0.f, 1.f - fabsf(sy - (float)(ylo + j)) / ks) : 0.f;
      wy[j] = w; wsy += w;
    }

    // vertical pass: wave wv reduces its plane's 8 rows into tmp[wv][.] (float2 loads).
    const float* rowp[8];
    #pragma unroll
    for (int j = 0; j < 8; j++) {
      int y = ylo + j; if (y > IH - 1) y = IH - 1;
      rowp[j] = mg + (size_t)y * IW;
    }
    for (int x2 = lane; x2 < IW / 2; x2 += 64) {
      float ax = 0.f, ay = 0.f;
      #pragma unroll
      for (int j = 0; j < 8; j++) {
        float2 v = *(const float2*)(rowp[j] + 2 * x2);
        ax += wy[j] * v.x;
        ay += wy[j] * v.y;
      }
      tmp[wv][2 * x2]     = ax;
      tmp[wv][2 * x2 + 1] = ay;
    }
    __syncthreads();   // LDS write->read visibility (tmp strips are wave-private)

    // horizontal pass + threshold: 138 outputs per wave (its own plane)
    unsigned char* op = dmp + (size_t)bn * NPX + (size_t)oy * PWD;
    for (int ox = lane; ox < PWD; ox += 64) {
      int xlo = s_xlo[ox];
      float vsum = 0.f;
      #pragma unroll
      for (int i = 0; i < 8; i++) {
        int xi = xlo + i; if (xi > IW - 1) xi = IW - 1;
        vsum += s_wx[ox][i] * tmp[wv][xi];
      }
      int bit = (vsum > 0.5f * wsy * s_wsx[ox]) ? 1 : 0;
      op[ox] = (unsigned char)bit;
      ones += bit;
    }
    __syncthreads();   // all reads of tmp done before next q overwrites
  }
  ones = wave_sum_i(ones);
  if (lane == 0) atomicAdd(&gtot[bn], ones);
}

// Mask loss v4: one block per (box, row-chunk); grid (64, 16). All k's sharing a
// box gi have the same rect/gt/inv, so:
//   Sum_k loss_k = inv * [ Sum_px_in_rect Sum_k (bce_k(px) - (gt?C_POS:C_NEGLO))
//                          + kn * (C_POS*Gt + C_NEGLO*(NPX-Gt)) ]
// Proto row loaded ONCE per pixel per box (registers); kn coefs in LDS
// (wave-uniform broadcast reads). 12.5x fewer proto loads than v3, 16x more
// blocks for latency hiding. Each block self-builds its k-list from pos_list.
__global__ __launch_bounds__(256) void maskloss_kernel(
    const float* __restrict__ proto_p, const float* __restrict__ coef_p,
    const float* __restrict__ box_gt, const int* __restrict__ pmi,
    const unsigned char* __restrict__ dmp, const int* __restrict__ pos_list,
    const int* __restrict__ npos_arr, const int* __restrict__ gtot,
    const float* __restrict__ scale_arr, float* accum)
{
  int bg = blockIdx.x;           // 0..63 = b*NOBJ + gi
  int b = bg >> 3, gi = bg & 7;
  int chunk = blockIdx.y;        // 0..15 row chunk
  int tid = threadIdx.x, wv = tid >> 6, lane = tid & 63;

  int np = npos_arr[b];
  int mb = np < 100 ? np : 100;

  __shared__ int s_klist[100];
  __shared__ int s_kn;
  if (tid == 0) s_kn = 0;
  __syncthreads();
  if (tid < mb) {
    int p = pos_list[b * 128 + tid];
    if (pmi[b * NP + p] == gi) {
      int slot = atomicAdd(&s_kn, 1);
      s_klist[slot] = p;
    }
  }
  __syncthreads();
  int kn = s_kn;
  if (kn == 0) return;   // uniform exit (no k maps to this box)

  // box rect (identical formulas to v3; validated absmax 0.0)
  const float* g = box_gt + (b * NOBJ + gi) * 4;
  float bx1 = g[0], by1 = g[1], bx2 = g[2], by2 = g[3];
  float ax = bx1 * 138.f, bx = bx2 * 138.f;
  float x1 = fminf(ax, bx), x2 = fmaxf(ax, bx);
  x1 = fmaxf(x1 - 1.f, 0.f); x2 = fminf(x2 + 1.f, 138.f);
  float ay = by1 * 138.f, by_ = by2 * 138.f;
  float y1 = fminf(ay, by_), y2 = fmaxf(ay, by_);
  y1 = fmaxf(y1 - 1.f, 0.f); y2 = fminf(y2 + 1.f, 138.f);
  float inv = 1.f / ((bx2 - bx1) * (by2 - by1));
  int xs = (int)ceilf(x1), xe = (int)ceilf(x2);
  int ys = (int)ceilf(y1), ye = (int)ceilf(y2);
  if (xe < xs) xe = xs;
  if (ye < ys) ye = ys;

  // coefs for this box's k's -> LDS (kn*128 B)
  __shared__ float s_cf[100 * NK];
  for (int i = tid; i < kn * NK; i += 256) {
    int kk = i >> 5, c = i & 31;
    s_cf[i] = coef_p[((size_t)(b * NP) + s_klist[kk]) * NK + c];
  }
  __syncthreads();

  const float C_POS   = 16.11809565f;     // -log(1e-7)
  const float C_NEGHI = 15.94238515f;     // -log1p(-0.99999988f)
  const float C_NEGLO = 1.00000005e-07f;  // -log1p(-1e-7f)
  float knf = (float)kn;

  const float* protoB = proto_p + (size_t)b * NPX * NK;
  const unsigned char* dpl = dmp + (size_t)(b * NOBJ + gi) * NPX;

  float lsum = 0.f;
  // rows: slot = chunk*4 + wv in [0,64), stride 64 (max rect height 138)
  for (int y = ys + chunk * 4 + wv; y < ye; y += 64) {
    const float* rowp = protoB + (size_t)y * PWD * NK;
    const unsigned char* rowg = dpl + y * PWD;
    for (int x = xs + lane; x < xe; x += 64) {
      const float4* pr = (const float4*)(rowp + (size_t)x * NK);
      float4 a0 = pr[0], a1 = pr[1], a2 = pr[2], a3 = pr[3];
      float4 a4 = pr[4], a5 = pr[5], a6 = pr[6], a7 = pr[7];
      int gbit = rowg[x];
      float base = gbit ? C_POS : C_NEGLO;
      float acc = -knf * base;    // fold out-of-rect constants per pixel
      for (int kk = 0; kk < kn; ++kk) {
        const float4* cf = (const float4*)&s_cf[kk * NK];
        float4 c0 = cf[0], c1 = cf[1], c2 = cf[2], c3 = cf[3];
        float4 c4 = cf[4], c5 = cf[5], c6 = cf[6], c7 = cf[7];
        float dot =
            a0.x*c0.x + a0.y*c0.y + a0.z*c0.z + a0.w*c0.w +
            a1.x*c1.x + a1.y*c1.y + a1.z*c1.z + a1.w*c1.w +
            a2.x*c2.x + a2.y*c2.y + a2.z*c2.z + a2.w*c2.w +
            a3.x*c3.x + a3.y*c3.y + a3.z*c3.z + a3.w*c3.w +
            a4.x*c4.x + a4.y*c4.y + a4.z*c4.z + a4.w*c4.w +
            a5.x*c5.x + a5.y*c5.y + a5.z*c5.z + a5.w*c5.w +
            a6.x*c6.x + a6.y*c6.y + a6.z*c6.z + a6.w*c6.w +
            a7.x*c7.x + a7.y*c7.y + a7.z*c7.z + a7.w*c7.w;
        float l = dot;
        float el = __expf(-fabsf(l));
        float sp = fmaxf(l, 0.f) + __logf(1.f + el);
        float t1 = fminf(sp - l, C_POS);
        float t2 = fminf(fmaxf(sp, C_NEGLO), C_NEGHI);
        acc += gbit ? t1 : t2;
      }
      lsum += acc;
    }
  }

  lsum = wave_sum(lsum);
  __shared__ float sl[4];
  if (lane == 0) sl[wv] = lsum;
  __syncthreads();
  if (tid == 0) {
    float L = sl[0] + sl[1] + sl[2] + sl[3];
    if (chunk == 0) {
      int Gt = gtot[bg];
      L += knf * (C_POS * (float)Gt + C_NEGLO * (float)(NPX - Gt));
    }
    atomicAdd(&accum[2], L * inv * scale_arr[b]);
  }
}

__global__ void finalize_kernel(const float* accum, float* out) {
  out[0] = 1.5f * accum[0] + accum[1] + accum[2] * (6.125f / (138.f * 138.f));
}

extern "C" void kernel_launch(void* const* d_in, const int* in_sizes, int n_in,
                              void* d_out, int out_size, void* d_ws, size_t ws_size,
                              hipStream_t stream) {
  const float* class_p  = (const float*)d_in[0];
  const float* box_p    = (const float*)d_in[1];
  const float* coef_p   = (const float*)d_in[2];
  const float* proto_p  = (const float*)d_in[3];
  const float* priors   = (const float*)d_in[4];
  const float* box_gt   = (const float*)d_in[5];
  const float* mask_gt  = (const float*)d_in[6];
  const int*   class_gt = (const int*)d_in[7];

  char* ws = (char*)d_ws;
  float* prior_max = (float*)(ws + 0);                 // NB*NP f32 = 615936 B
  int*   prior_arg = (int*)(ws + 615936);              // NB*NP i32
  int*   conf      = (int*)(ws + 1231872);             // NB*NP i32
  float* marks     = (float*)(ws + 1847808);           // NB*NP f32
  unsigned char* dmp = (unsigned char*)(ws + 2463744); // NB*NOBJ*NPX u8 = 1218816
  int*   pos_list  = (int*)(ws + 3682560);             // NB*128 i32 = 4096
  int*   npos_arr  = (int*)(ws + 3686656);             // NB i32
  int*   nneg_arr  = (int*)(ws + 3686688);             // NB i32
  float* scale_arr = (float*)(ws + 3686720);           // NB f32
  float* accum     = (float*)(ws + 3686752);           // 4 f32  (memset region start)
  unsigned long long* forced = (unsigned long long*)(ws + 3686768); // NB*NOBJ u64 = 512
  int*   gtot      = (int*)(ws + 3687280);             // NB*NOBJ i32 = 256 (memset'd)
  int*   blkcnt    = (int*)(ws + 3687536);             // NB*NBLK i32 = 2432
  (void)in_sizes; (void)n_in; (void)out_size; (void)ws_size;

  // zero accum (16B) + forced (512B) + gtot (256B) in one memset node
  hipMemsetAsync((void*)accum, 0, 16 + 512 + 256, stream);

  {
    dim3 g(NBLK, NB);
    match1_kernel<<<g, 256, 0, stream>>>(priors, box_gt, prior_max, prior_arg, forced);
    conf_kernel<<<g, 256, 0, stream>>>(priors, box_gt, class_gt, box_p,
                                       prior_max, prior_arg, forced, conf, blkcnt, accum);
    scatter_kernel<<<g, 256, 0, stream>>>(conf, blkcnt, pos_list,
                                          npos_arr, nneg_arr, scale_arr);
  }
  mark_kernel<<<MGRID, 256, 0, stream>>>(class_p, conf, marks, accum);
  select_kernel<<<NB, 256, 0, stream>>>(marks, nneg_arr, accum);
  {
    dim3 g(NB * NOBJ / 4, PHD / 6);   // (plane-group, oy-group)
    resize_kernel<<<g, 256, 0, stream>>>(mask_gt, dmp, gtot);
  }
  {
    dim3 g(NB * NOBJ, 16);   // (box, row-chunk)
    maskloss_kernel<<<g, 256, 0, stream>>>(proto_p, coef_p, box_gt, prior_arg, dmp,
                                           pos_list, npos_arr, gtot, scale_arr, accum);
  }
  finalize_kernel<<<1, 1, 0, stream>>>(accum, (float*)d_out);
}

// Round 6
// 282.984 us; speedup vs baseline: 1.2916x; 1.2078x over previous
//
#include <hip/hip_runtime.h>
#include <math.h>

#define NB 8
#define NP 19248
#define NC 81
#define NOBJ 8
#define NK 32
#define PHD 138
#define PWD 138
#define NPX (PHD * PWD)   // 19044
#define IH 550
#define IW 550
#define NBLK 76           // ceil(NP/256)
#define MROWG 9624        // (NB*NP)/16 row-groups for mark
#define MGRID 1203        // mark grid: 8 row-groups per block
#define BFSTRIDE 80       // blkfmax row stride (u64)

typedef short v8s __attribute__((ext_vector_type(8)));
typedef float v4f __attribute__((ext_vector_type(4)));

__device__ __forceinline__ float wave_sum(float v) {
  #pragma unroll
  for (int o = 32; o >= 1; o >>= 1) v += __shfl_xor(v, o);
  return v;
}
__device__ __forceinline__ int wave_sum_i(int v) {
  #pragma unroll
  for (int o = 32; o >= 1; o >>= 1) v += __shfl_xor(v, o);
  return v;
}
__device__ __forceinline__ unsigned short f2bf(float f) {
  unsigned u = __float_as_uint(f);
  u = (u + 0x7fffu + ((u >> 16) & 1u)) >> 16;
  return (unsigned short)u;
}

// grid (76, NB): one prior per thread. Per-prior max/arg; per-gt per-BLOCK max via
// LDS reduction + plain store to blkfmax[b*NOBJ+j][bx] (NO atomics — the old
// 19456 same-line atomicMax u64 ops serialized at ~2.6ns each = ~50us).
__global__ __launch_bounds__(256) void match1_kernel(
    const float* __restrict__ priors, const float* __restrict__ box_gt,
    float* __restrict__ prior_max, int* __restrict__ prior_arg,
    unsigned long long* __restrict__ blkfmax)
{
  int b = blockIdx.y, bx = blockIdx.x, tid = threadIdx.x;
  int p = bx * 256 + tid;
  int lane = tid & 63, wid = tid >> 6;
  __shared__ float gx1[NOBJ], gy1[NOBJ], gx2[NOBJ], gy2[NOBJ], garea[NOBJ];
  __shared__ unsigned long long s_red[4][NOBJ];
  if (tid < NOBJ) {
    const float* g = box_gt + (b * NOBJ + tid) * 4;
    float x1 = g[0], y1 = g[1], x2 = g[2], y2 = g[3];
    gx1[tid] = x1; gy1[tid] = y1; gx2[tid] = x2; gy2[tid] = y2;
    garea[tid] = (x2 - x1) * (y2 - y1);
  }
  __syncthreads();

  bool act = p < NP;
  float dx1 = 0, dy1 = 0, dx2 = 0, dy2 = 0, darea = 1.f;
  if (act) {
    const float* pr = priors + p * 4;
    float cx = pr[0], cy = pr[1], w = pr[2], h = pr[3];
    dx1 = cx - w * 0.5f; dy1 = cy - h * 0.5f;
    dx2 = cx + w * 0.5f; dy2 = cy + h * 0.5f;
    darea = (dx2 - dx1) * (dy2 - dy1);
  }
  float pmax = -1.f; int parg = 0;
  unsigned long long pk[NOBJ];
  #pragma unroll
  for (int j = 0; j < NOBJ; j++) {
    float ix = fmaxf(fminf(gx2[j], dx2) - fmaxf(gx1[j], dx1), 0.f);
    float iy = fmaxf(fminf(gy2[j], dy2) - fmaxf(gy1[j], dy1), 0.f);
    float inter = ix * iy;
    float iou = inter / (garea[j] + darea - inter);
    if (j == 0) { pmax = iou; parg = 0; }
    else if (iou > pmax) { pmax = iou; parg = j; }   // strict > : first-index tie-break
    pk[j] = act ? ((((unsigned long long)__float_as_uint(iou)) << 32)
                   | (unsigned long long)(0x7fffffffu - (unsigned)p))
                : 0ull;
  }
  if (act) {
    prior_max[b * NP + p] = pmax;
    prior_arg[b * NP + p] = parg;
  }
  #pragma unroll
  for (int j = 0; j < NOBJ; j++) {
    unsigned long long v = pk[j];
    #pragma unroll
    for (int o = 32; o >= 1; o >>= 1) {
      unsigned long long ov = __shfl_xor(v, o);
      if (ov > v) v = ov;
    }
    if (lane == 0) s_red[wid][j] = v;
  }
  __syncthreads();
  if (tid < NOBJ) {
    unsigned long long v = s_red[0][tid];
    #pragma unroll
    for (int w = 1; w < 4; w++) { unsigned long long t = s_red[w][tid]; if (t > v) v = t; }
    blkfmax[(size_t)(b * NOBJ + tid) * BFSTRIDE + bx] = v;
  }
}

// grid (76, NB): reconstruct per-box winners from blkfmax (wave-parallel reduce),
// forced-match override + conf + smooth-L1 box loss -> blkloss (plain store).
__global__ __launch_bounds__(256) void conf_kernel(
    const float* __restrict__ priors, const float* __restrict__ box_gt,
    const int* __restrict__ class_gt, const float* __restrict__ box_p,
    const float* __restrict__ prior_max, int* __restrict__ prior_arg,
    const unsigned long long* __restrict__ blkfmax,
    int* __restrict__ conf, int* __restrict__ blkcnt, float* __restrict__ blkloss)
{
  int b = blockIdx.y, bx = blockIdx.x, tid = threadIdx.x;
  int p = bx * 256 + tid;
  int lane = tid & 63, wid = tid >> 6;
  __shared__ int s_fi[NOBJ];
  __shared__ float lbw[4];
  __shared__ int pcw[4];
  // wave wid reduces boxes j = wid*2, wid*2+1 over the 76 block maxima
  #pragma unroll
  for (int jj = 0; jj < 2; jj++) {
    int j = wid * 2 + jj;
    const unsigned long long* bp_ = blkfmax + (size_t)(b * NOBJ + j) * BFSTRIDE;
    unsigned long long v = (lane < NBLK) ? bp_[lane] : 0ull;
    if (lane + 64 < NBLK) { unsigned long long t = bp_[lane + 64]; if (t > v) v = t; }
    #pragma unroll
    for (int o = 32; o >= 1; o >>= 1) {
      unsigned long long ov = __shfl_xor(v, o);
      if (ov > v) v = ov;
    }
    if (lane == 0) s_fi[j] = 0x7fffffff - (int)(v & 0xffffffffull);
  }
  __syncthreads();
  float lb = 0.f;
  bool flag = false;
  if (p < NP) {
    float m = prior_max[b * NP + p];
    int j = prior_arg[b * NP + p];
    int ov = -1;
    #pragma unroll
    for (int jj = 0; jj < NOBJ; jj++)
      if (p == s_fi[jj]) ov = jj;      // later j wins
    if (ov >= 0) { m = 2.0f; j = ov; prior_arg[b * NP + p] = ov; }
    int cf = class_gt[b * NOBJ + j] + 1;
    if (m < 0.5f) cf = -1;
    if (m < 0.4f) cf = 0;
    conf[b * NP + p] = cf;
    flag = cf > 0;
    if (flag) {
      const float* g = box_gt + (b * NOBJ + j) * 4;
      float x1 = g[0], y1 = g[1], x2 = g[2], y2 = g[3];
      const float* pr = priors + p * 4;
      float pcx = pr[0], pcy = pr[1], prw = pr[2], prh = pr[3];
      float o4[4];
      o4[0] = ((x1 + x2) * 0.5f - pcx) / (0.1f * prw);
      o4[1] = ((y1 + y2) * 0.5f - pcy) / (0.1f * prh);
      o4[2] = logf((x2 - x1) / prw) / 0.2f;
      o4[3] = logf((y2 - y1) / prh) / 0.2f;
      const float* bp = box_p + (b * NP + p) * 4;
      #pragma unroll
      for (int c = 0; c < 4; c++) {
        float d = fabsf(bp[c] - o4[c]);
        lb += (d < 1.f) ? 0.5f * d * d : d - 0.5f;
      }
    }
  }
  unsigned long long bm = __ballot(flag);
  lb = wave_sum(lb);
  if (lane == 0) { lbw[wid] = lb; pcw[wid] = __popcll(bm); }
  __syncthreads();
  if (tid == 0) {
    blkloss[b * NBLK + bx] = lbw[0] + lbw[1] + lbw[2] + lbw[3];
    blkcnt[b * NBLK + bx] = pcw[0] + pcw[1] + pcw[2] + pcw[3];
  }
}

// grid (76, NB): ordered compaction using blkcnt prefix; last block writes
// npos/nneg/scale and reduces blkloss -> accum[0] (8 atomics total).
__global__ __launch_bounds__(256) void scatter_kernel(
    const int* __restrict__ conf, const int* __restrict__ blkcnt,
    const float* __restrict__ blkloss,
    int* __restrict__ pos_list, int* __restrict__ npos_arr,
    int* __restrict__ nneg_arr, float* __restrict__ scale_arr, float* accum)
{
  int bx = blockIdx.x, b = blockIdx.y, tid = threadIdx.x;
  int lane = tid & 63, wid = tid >> 6;
  __shared__ int s_pre;
  __shared__ int wc[4];
  if (tid < 64) {
    int s = 0;
    if (tid < bx) s += blkcnt[b * NBLK + tid];
    int t2 = tid + 64;
    if (t2 < bx) s += blkcnt[b * NBLK + t2];
    s = wave_sum_i(s);
    if (tid == 0) s_pre = s;
  }
  int p = bx * 256 + tid;
  bool flag = (p < NP) && (conf[b * NP + p] > 0);
  unsigned long long m = __ballot(flag);
  if (lane == 0) wc[wid] = __popcll(m);
  __syncthreads();
  int base = s_pre;
  for (int w = 0; w < wid; w++) base += wc[w];
  int idx = base + __popcll(m & ((1ull << lane) - 1ull));
  if (flag && idx < 128) pos_list[b * 128 + idx] = p;
  if (bx == NBLK - 1) {
    if (tid == 0) {
      int np = s_pre + wc[0] + wc[1] + wc[2] + wc[3];
      npos_arr[b] = np;
      int nn = 3 * np; if (nn > NP - 1) nn = NP - 1;
      nneg_arr[b] = nn;
      scale_arr[b] = (np > 100) ? (float)np / 100.0f : 1.0f;
    }
    if (tid < 64) {
      float s = (tid < NBLK) ? blkloss[b * NBLK + tid] : 0.f;
      if (tid + 64 < NBLK) s += blkloss[b * NBLK + tid + 64];
      s = wave_sum(s);
      if (tid == 0) atomicAdd(&accum[0], s);
    }
  }
}

// mark v3: grid-stride, positive-NLL per block -> spread atomic slots (8 lines).
__global__ __launch_bounds__(256) void mark_kernel(
    const float* __restrict__ class_p, const int* __restrict__ conf,
    float* __restrict__ marks, float* __restrict__ asp)
{
  int lane = threadIdx.x & 63, wv = threadIdx.x >> 6;
  int sub = lane & 15, grp = lane >> 4;
  __shared__ float sred[4];
  float acc1 = 0.f;
  for (int gblk = blockIdx.x; gblk < MROWG; gblk += MGRID) {
    int row = gblk * 16 + wv * 4 + grp;
    const float* cp = class_p + (size_t)row * NC;
    float v[6];
    #pragma unroll
    for (int k = 0; k < 6; k++) {
      int c = sub + 16 * k;
      v[k] = (c < NC) ? cp[c] : -INFINITY;
    }
    float m = v[0];
    #pragma unroll
    for (int k = 1; k < 6; k++) m = fmaxf(m, v[k]);
    #pragma unroll
    for (int o = 1; o < 16; o <<= 1) m = fmaxf(m, __shfl_xor(m, o));
    float s = 0.f;
    #pragma unroll
    for (int k = 0; k < 6; k++) s += __expf(v[k] - m);
    #pragma unroll
    for (int o = 1; o < 16; o <<= 1) s += __shfl_xor(s, o);
    float lse = m + __logf(s);
    if (sub == 0) {
      int cf = conf[row];
      marks[row] = (cf != 0) ? 0.f : (lse - v[0]);
      if (cf > 0) acc1 += lse - cp[cf];
    }
  }
  acc1 = wave_sum(acc1);
  if (lane == 0) sred[wv] = acc1;
  __syncthreads();
  if (threadIdx.x == 0)
    atomicAdd(&asp[(blockIdx.x & 7) * 16], sred[0] + sred[1] + sred[2] + sred[3]);
}

// Per batch, 256 threads x 76 regs: 31-step binary search on uint bits; sum of top-k marks.
__global__ __launch_bounds__(256) void select_kernel(
    const float* __restrict__ marks, const int* __restrict__ nneg_arr,
    float* __restrict__ asp)
{
  int b = blockIdx.x, tid = threadIdx.x;
  int lane = tid & 63, wid = tid >> 6;
  float v[NBLK];
  #pragma unroll
  for (int i = 0; i < NBLK; i++) {
    int p = i * 256 + tid;
    v[i] = (p < NP) ? marks[b * NP + p] : 0.f;  // pad 0: midpoints > 0, pads never counted
  }
  int k = nneg_arr[b];
  __shared__ unsigned slo, shi;
  __shared__ int wred[4];
  __shared__ float fred[4];
  if (tid == 0) { slo = 0u; shi = 0x7f800000u; }
  __syncthreads();
  while (true) {
    unsigned lo = slo, hi = shi;
    if (hi - lo <= 1u) break;
    unsigned mid = lo + ((hi - lo) >> 1);
    float fmid = __uint_as_float(mid);
    int cnt = 0;
    #pragma unroll
    for (int i = 0; i < NBLK; i++) cnt += (v[i] >= fmid) ? 1 : 0;
    cnt = wave_sum_i(cnt);
    if (lane == 0) wred[wid] = cnt;
    __syncthreads();
    if (tid == 0) {
      int tot = wred[0] + wred[1] + wred[2] + wred[3];
      if (tot >= k) slo = mid; else shi = mid;
    }
    __syncthreads();
  }
  float thr = __uint_as_float(slo);
  float s = 0.f;
  #pragma unroll
  for (int i = 0; i < NBLK; i++) if (v[i] >= thr) s += v[i];
  s = wave_sum(s);
  if (lane == 0) fred[wid] = s;
  __syncthreads();
  if (tid == 0) atomicAdd(&asp[(b & 7) * 16], fred[0] + fred[1] + fred[2] + fred[3]);
}

// Separable antialiased resize v4. Block = (plane-group of 4, oy-group of 6).
// Each wave owns one plane; also counts the 1-bits it writes -> gtot[plane].
__global__ __launch_bounds__(256) void resize_kernel(
    const float* __restrict__ mask_gt, unsigned char* __restrict__ dmp,
    int* __restrict__ gtot)
{
  int pg = blockIdx.x;         // plane group 0..15
  int tid = threadIdx.x;
  int wv = tid >> 6, lane = tid & 63;
  int bn = pg * 4 + wv;        // plane 0..63

  __shared__ float tmp[4][IW];       // per-wave vertical-pass rows (8800 B)
  __shared__ float s_wx[PWD][9];     // horizontal weights, padded stride 9 (4968 B)
  __shared__ float s_wsx[PWD];
  __shared__ int   s_xlo[PWD];

  const float ks = (float)IH / (float)PHD;  // 550/138

  if (tid < PWD) {
    int ox = tid;
    float sx = (ox + 0.5f) * ks - 0.5f;
    int xlo = (int)ceilf(sx - ks); if (xlo < 0) xlo = 0;
    int xhi = (int)floorf(sx + ks); if (xhi > IW - 1) xhi = IW - 1;
    int nx = xhi - xlo;
    float wsx = 0.f;
    #pragma unroll
    for (int i = 0; i < 8; i++) {
      float w = (i <= nx) ? fmaxf(0.f, 1.f - fabsf(sx - (float)(xlo + i)) / ks) : 0.f;
      s_wx[ox][i] = w; wsx += w;
    }
    s_xlo[ox] = xlo;
    s_wsx[ox] = wsx;
  }
  __syncthreads();

  const float* mg = mask_gt + (size_t)bn * (IH * IW);
  int ones = 0;

  for (int q = 0; q < 6; ++q) {
    int oy = blockIdx.y * 6 + q;   // 0..137 (138 = 23*6)

    float sy = (oy + 0.5f) * ks - 0.5f;
    int ylo = (int)ceilf(sy - ks); if (ylo < 0) ylo = 0;
    int yhi = (int)floorf(sy + ks); if (yhi > IH - 1) yhi = IH - 1;
    int ny = yhi - ylo;   // <= 7
    float wy[8]; float wsy = 0.f;
    #pragma unroll
    for (int j = 0; j < 8; j++) {
      float w = (j <= ny) ? fmaxf(0.f, 1.f - fabsf(sy - (float)(ylo + j)) / ks) : 0.f;
      wy[j] = w; wsy += w;
    }

    const float* rowp[8];
    #pragma unroll
    for (int j = 0; j < 8; j++) {
      int y = ylo + j; if (y > IH - 1) y = IH - 1;
      rowp[j] = mg + (size_t)y * IW;
    }
    for (int x2 = lane; x2 < IW / 2; x2 += 64) {
      float ax = 0.f, ay = 0.f;
      #pragma unroll
      for (int j = 0; j < 8; j++) {
        float2 v = *(const float2*)(rowp[j] + 2 * x2);
        ax += wy[j] * v.x;
        ay += wy[j] * v.y;
      }
      tmp[wv][2 * x2]     = ax;
      tmp[wv][2 * x2 + 1] = ay;
    }
    __syncthreads();

    unsigned char* op = dmp + (size_t)bn * NPX + (size_t)oy * PWD;
    for (int ox = lane; ox < PWD; ox += 64) {
      int xlo = s_xlo[ox];
      float vsum = 0.f;
      #pragma unroll
      for (int i = 0; i < 8; i++) {
        int xi = xlo + i; if (xi > IW - 1) xi = IW - 1;
        vsum += s_wx[ox][i] * tmp[wv][xi];
      }
      int bit = (vsum > 0.5f * wsy * s_wsx[ox]) ? 1 : 0;
      op[ox] = (unsigned char)bit;
      ones += bit;
    }
    __syncthreads();
  }
  ones = wave_sum_i(ones);
  if (lane == 0) atomicAdd(&gtot[bn], ones);
}

// Mask loss v4 (+spread atomics): one block per (box, row-chunk); grid (64, 16).
__global__ __launch_bounds__(256) void maskloss_kernel(
    const float* __restrict__ proto_p, const float* __restrict__ coef_p,
    const float* __restrict__ box_gt, const int* __restrict__ pmi,
    const unsigned char* __restrict__ dmp, const int* __restrict__ pos_list,
    const int* __restrict__ npos_arr, const int* __restrict__ gtot,
    const float* __restrict__ scale_arr, float* __restrict__ asp)
{
  int bg = blockIdx.x;           // 0..63 = b*NOBJ + gi
  int b = bg >> 3, gi = bg & 7;
  int chunk = blockIdx.y;        // 0..15 row chunk
  int tid = threadIdx.x, wv = tid >> 6, lane = tid & 63;

  int np = npos_arr[b];
  int mb = np < 100 ? np : 100;

  __shared__ int s_klist[100];
  __shared__ int s_kn;
  if (tid == 0) s_kn = 0;
  __syncthreads();
  if (tid < mb) {
    int p = pos_list[b * 128 + tid];
    if (pmi[b * NP + p] == gi) {
      int slot = atomicAdd(&s_kn, 1);
      s_klist[slot] = p;
    }
  }
  __syncthreads();
  int kn = s_kn;
  if (kn == 0) return;   // uniform exit (no k maps to this box)

  const float* g = box_gt + (b * NOBJ + gi) * 4;
  float bx1 = g[0], by1 = g[1], bx2 = g[2], by2 = g[3];
  float ax = bx1 * 138.f, bx = bx2 * 138.f;
  float x1 = fminf(ax, bx), x2 = fmaxf(ax, bx);
  x1 = fmaxf(x1 - 1.f, 0.f); x2 = fminf(x2 + 1.f, 138.f);
  float ay = by1 * 138.f, by_ = by2 * 138.f;
  float y1 = fminf(ay, by_), y2 = fmaxf(ay, by_);
  y1 = fmaxf(y1 - 1.f, 0.f); y2 = fminf(y2 + 1.f, 138.f);
  float inv = 1.f / ((bx2 - bx1) * (by2 - by1));
  int xs = (int)ceilf(x1), xe = (int)ceilf(x2);
  int ys = (int)ceilf(y1), ye = (int)ceilf(y2);
  if (xe < xs) xe = xs;
  if (ye < ys) ye = ys;

  __shared__ float s_cf[100 * NK];
  for (int i = tid; i < kn * NK; i += 256) {
    int kk = i >> 5, c = i & 31;
    s_cf[i] = coef_p[((size_t)(b * NP) + s_klist[kk]) * NK + c];
  }
  __syncthreads();

  const float C_POS   = 16.11809565f;     // -log(1e-7)
  const float C_NEGHI = 15.94238515f;     // -log1p(-0.99999988f)
  const float C_NEGLO = 1.00000005e-07f;  // -log1p(-1e-7f)
  float knf = (float)kn;

  const float* protoB = proto_p + (size_t)b * NPX * NK;
  const unsigned char* dpl = dmp + (size_t)(b * NOBJ + gi) * NPX;

  float lsum = 0.f;
  for (int y = ys + chunk * 4 + wv; y < ye; y += 64) {
    const float* rowp = protoB + (size_t)y * PWD * NK;
    const unsigned char* rowg = dpl + y * PWD;
    for (int x = xs + lane; x < xe; x += 64) {
      const float4* pr = (const float4*)(rowp + (size_t)x * NK);
      float4 a0 = pr[0], a1 = pr[1], a2 = pr[2], a3 = pr[3];
      float4 a4 = pr[4], a5 = pr[5], a6 = pr[6], a7 = pr[7];
      int gbit = rowg[x];
      float base = gbit ? C_POS : C_NEGLO;
      float acc = -knf * base;    // fold out-of-rect constants per pixel
      for (int kk = 0; kk < kn; ++kk) {
        const float4* cf = (const float4*)&s_cf[kk * NK];
        float4 c0 = cf[0], c1 = cf[1], c2 = cf[2], c3 = cf[3];
        float4 c4 = cf[4], c5 = cf[5], c6 = cf[6], c7 = cf[7];
        float dot =
            a0.x*c0.x + a0.y*c0.y + a0.z*c0.z + a0.w*c0.w +
            a1.x*c1.x + a1.y*c1.y + a1.z*c1.z + a1.w*c1.w +
            a2.x*c2.x + a2.y*c2.y + a2.z*c2.z + a2.w*c2.w +
            a3.x*c3.x + a3.y*c3.y + a3.z*c3.z + a3.w*c3.w +
            a4.x*c4.x + a4.y*c4.y + a4.z*c4.z + a4.w*c4.w +
            a5.x*c5.x + a5.y*c5.y + a5.z*c5.z + a5.w*c5.w +
            a6.x*c6.x + a6.y*c6.y + a6.z*c6.z + a6.w*c6.w +
            a7.x*c7.x + a7.y*c7.y + a7.z*c7.z + a7.w*c7.w;
        float l = dot;
        float el = __expf(-fabsf(l));
        float sp = fmaxf(l, 0.f) + __logf(1.f + el);
        float t1 = fminf(sp - l, C_POS);
        float t2 = fminf(fmaxf(sp, C_NEGLO), C_NEGHI);
        acc += gbit ? t1 : t2;
      }
      lsum += acc;
    }
  }

  lsum = wave_sum(lsum);
  __shared__ float sl[4];
  if (lane == 0) sl[wv] = lsum;
  __syncthreads();
  if (tid == 0) {
    float L = sl[0] + sl[1] + sl[2] + sl[3];
    if (chunk == 0) {
      int Gt = gtot[bg];
      L += knf * (C_POS * (float)Gt + C_NEGLO * (float)(NPX - Gt));
    }
    atomicAdd(&asp[128 + (bg & 7) * 16], L * inv * scale_arr[b]);
  }
}

__global__ void finalize_kernel(const float* accum, const float* asp, float* out) {
  float c1 = 0.f, c2 = 0.f;
  #pragma unroll
  for (int i = 0; i < 8; i++) { c1 += asp[i * 16]; c2 += asp[128 + i * 16]; }
  out[0] = 1.5f * accum[0] + c1 + c2 * (6.125f / (138.f * 138.f));
}

extern "C" void kernel_launch(void* const* d_in, const int* in_sizes, int n_in,
                              void* d_out, int out_size, void* d_ws, size_t ws_size,
                              hipStream_t stream) {
  const float* class_p  = (const float*)d_in[0];
  const float* box_p    = (const float*)d_in[1];
  const float* coef_p   = (const float*)d_in[2];
  const float* proto_p  = (const float*)d_in[3];
  const float* priors   = (const float*)d_in[4];
  const float* box_gt   = (const float*)d_in[5];
  const float* mask_gt  = (const float*)d_in[6];
  const int*   class_gt = (const int*)d_in[7];

  char* ws = (char*)d_ws;
  float* prior_max = (float*)(ws + 0);                 // NB*NP f32 = 615936 B
  int*   prior_arg = (int*)(ws + 615936);              // NB*NP i32
  int*   conf      = (int*)(ws + 1231872);             // NB*NP i32
  float* marks     = (float*)(ws + 1847808);           // NB*NP f32
  unsigned long long* blkfmax = (unsigned long long*)marks; // alias: dead until mark_kernel
  unsigned char* dmp = (unsigned char*)(ws + 2463744); // NB*NOBJ*NPX u8 = 1218816
  int*   pos_list  = (int*)(ws + 3682560);             // NB*128 i32 = 4096
  int*   npos_arr  = (int*)(ws + 3686656);             // NB i32
  int*   nneg_arr  = (int*)(ws + 3686688);             // NB i32
  float* scale_arr = (float*)(ws + 3686720);           // NB f32
  float* blkloss   = (float*)(ws + 3686752);           // NB*NBLK f32 = 2432
  int*   blkcnt    = (int*)(ws + 3689184);             // NB*NBLK i32 = 2432
  // ---- memset region: accum(64) + gtot(256) + asp(1024) = 1344 B ----
  float* accum     = (float*)(ws + 3691616);           // [0] box loss
  int*   gtot      = (int*)(ws + 3691680);             // NB*NOBJ i32 = 256
  float* asp       = (float*)(ws + 3691936);           // 2ch x 8 slots x 64B
  (void)in_sizes; (void)n_in; (void)out_size; (void)ws_size;

  hipMemsetAsync((void*)accum, 0, 1344, stream);

  {
    dim3 g(NBLK, NB);
    match1_kernel<<<g, 256, 0, stream>>>(priors, box_gt, prior_max, prior_arg, blkfmax);
    conf_kernel<<<g, 256, 0, stream>>>(priors, box_gt, class_gt, box_p,
                                       prior_max, prior_arg, blkfmax, conf, blkcnt, blkloss);
    scatter_kernel<<<g, 256, 0, stream>>>(conf, blkcnt, blkloss, pos_list,
                                          npos_arr, nneg_arr, scale_arr, accum);
  }
  mark_kernel<<<MGRID, 256, 0, stream>>>(class_p, conf, marks, asp);
  select_kernel<<<NB, 256, 0, stream>>>(marks, nneg_arr, asp);
  {
    dim3 g(NB * NOBJ / 4, PHD / 6);   // (plane-group, oy-group)
    resize_kernel<<<g, 256, 0, stream>>>(mask_gt, dmp, gtot);
  }
  {
    dim3 g(NB * NOBJ, 16);   // (box, row-chunk)
    maskloss_kernel<<<g, 256, 0, stream>>>(proto_p, coef_p, box_gt, prior_arg, dmp,
                                           pos_list, npos_arr, gtot, scale_arr, asp);
  }
  finalize_kernel<<<1, 1, 0, stream>>>(accum, asp, (float*)d_out);
}